// Round 12
// baseline (344.987 us; speedup 1.0000x reference)
//
#include <hip/hip_runtime.h>
#include <hip/hip_bf16.h>
#include <hip/hip_cooperative_groups.h>

namespace cg = cooperative_groups;

#define NN 1024
#define NE 32768
#define TAU 0.7f
#define GAPT 0.01f

typedef __attribute__((ext_vector_type(8))) short short8;
typedef __attribute__((ext_vector_type(4))) float f32x4;

__device__ inline ushort bf16rne(float x) {
    union { float f; unsigned u; } a; a.f = x;
    unsigned r = (a.u + 0x7FFFu + ((a.u >> 16) & 1u)) >> 16;
    return (ushort)r;
}
__device__ inline float bf16tof(ushort h) {
    union { unsigned u; float f; } a; a.u = ((unsigned)h) << 16;
    return a.f;
}
__device__ inline void bf16split(float x, ushort& h, ushort& l) {
    h = bf16rne(x);
    l = bf16rne(x - bf16tof(h));
}

// =============== bf16x3 MFMA wave job: 16 rows x 32 cols, full K ===============
template <int K, int EPI>
__device__ __forceinline__ void gemm_wave(
    int lane, int rt, int ct,
    const ushort* __restrict__ Ah, const ushort* __restrict__ Al,
    const ushort* __restrict__ Bh, const ushort* __restrict__ Bl,
    const float* __restrict__ bias, const float* __restrict__ W3,
    float* __restrict__ Cf, ushort* __restrict__ Oh, ushort* __restrict__ Ol, int N) {
    int r0 = rt * 16, c0 = ct * 32;
    int g = lane >> 4, q = lane & 15;
    const ushort* pah = Ah + (size_t)(r0 + q) * K + g * 8;
    const ushort* pal = Al + (size_t)(r0 + q) * K + g * 8;
    const ushort* pb0h = Bh + (size_t)(c0 + q) * K + g * 8;
    const ushort* pb0l = Bl + (size_t)(c0 + q) * K + g * 8;
    const ushort* pb1h = pb0h + (size_t)16 * K;
    const ushort* pb1l = pb0l + (size_t)16 * K;
    f32x4 acc0 = {0.f, 0.f, 0.f, 0.f};
    f32x4 acc1 = {0.f, 0.f, 0.f, 0.f};
#pragma unroll 2
    for (int k0 = 0; k0 < K; k0 += 32) {
        short8 ah = *(const short8*)(pah + k0);
        short8 al = *(const short8*)(pal + k0);
        short8 b0h = *(const short8*)(pb0h + k0);
        short8 b0l = *(const short8*)(pb0l + k0);
        short8 b1h = *(const short8*)(pb1h + k0);
        short8 b1l = *(const short8*)(pb1l + k0);
        acc0 = __builtin_amdgcn_mfma_f32_16x16x32_bf16(ah, b0h, acc0, 0, 0, 0);
        acc1 = __builtin_amdgcn_mfma_f32_16x16x32_bf16(ah, b1h, acc1, 0, 0, 0);
        acc0 = __builtin_amdgcn_mfma_f32_16x16x32_bf16(ah, b0l, acc0, 0, 0, 0);
        acc1 = __builtin_amdgcn_mfma_f32_16x16x32_bf16(ah, b1l, acc1, 0, 0, 0);
        acc0 = __builtin_amdgcn_mfma_f32_16x16x32_bf16(al, b0h, acc0, 0, 0, 0);
        acc1 = __builtin_amdgcn_mfma_f32_16x16x32_bf16(al, b1h, acc1, 0, 0, 0);
    }
    int col0 = c0 + q, col1 = c0 + 16 + q;
    if constexpr (EPI == 0) {
#pragma unroll
        for (int i = 0; i < 4; i++) {
            int row = r0 + g * 4 + i;
            Cf[(size_t)row * N + col0] = acc0[i];
            Cf[(size_t)row * N + col1] = acc1[i];
        }
    } else if constexpr (EPI == 1) {
        float bv0 = bias[col0], bv1 = bias[col1];
#pragma unroll
        for (int i = 0; i < 4; i++) {
            int row = r0 + g * 4 + i;
            float a0 = fmaxf(acc0[i] + bv0, 0.f);
            float a1 = fmaxf(acc1[i] + bv1, 0.f);
            ushort h, l;
            bf16split(a0, h, l);
            Oh[(size_t)row * N + col0] = h;
            Ol[(size_t)row * N + col0] = l;
            bf16split(a1, h, l);
            Oh[(size_t)row * N + col1] = h;
            Ol[(size_t)row * N + col1] = l;
        }
    } else {
        constexpr int J = (EPI == 2) ? 3 : 2;
        constexpr int STR = (EPI == 2) ? 4 : 2;
        float bv0 = bias[col0], bv1 = bias[col1];
        float s[4][J];
#pragma unroll
        for (int i = 0; i < 4; i++) {
            float a0 = fmaxf(acc0[i] + bv0, 0.f);
            float a1 = fmaxf(acc1[i] + bv1, 0.f);
#pragma unroll
            for (int j = 0; j < J; j++)
                s[i][j] = a0 * W3[col0 * J + j] + a1 * W3[col1 * J + j];
        }
#pragma unroll
        for (int i = 0; i < 4; i++)
#pragma unroll
            for (int j = 0; j < J; j++) {
                float v = s[i][j];
#pragma unroll
                for (int m = 1; m < 16; m <<= 1) v += __shfl_xor(v, m);
                s[i][j] = v;
            }
        if (q == 0) {
#pragma unroll
            for (int i = 0; i < 4; i++) {
                int row = r0 + g * 4 + i;
#pragma unroll
                for (int j = 0; j < J; j++) atomicAdd(&Cf[(size_t)row * STR + j], s[i][j]);
            }
        }
    }
}

// 16-col variant (fallback D5)
template <int M, int N, int K>
__global__ __launch_bounds__(256) void gemm3_n16(
    const ushort* __restrict__ Ah, const ushort* __restrict__ Al,
    const ushort* __restrict__ Bh, const ushort* __restrict__ Bl,
    float* __restrict__ Cf) {
    constexpr int RT = M / 16;
    constexpr int JOBS = RT * (N / 16);
    int wid = (blockIdx.x * 256 + threadIdx.x) >> 6;
    if (wid >= JOBS) return;
    int lane = threadIdx.x & 63;
    int rt = wid % RT, ct = wid / RT;
    int r0 = rt * 16, c0 = ct * 16;
    int g = lane >> 4, q = lane & 15;
    const ushort* pah = Ah + (size_t)(r0 + q) * K + g * 8;
    const ushort* pal = Al + (size_t)(r0 + q) * K + g * 8;
    const ushort* pbh = Bh + (size_t)(c0 + q) * K + g * 8;
    const ushort* pbl = Bl + (size_t)(c0 + q) * K + g * 8;
    f32x4 acc = {0.f, 0.f, 0.f, 0.f};
#pragma unroll 2
    for (int k0 = 0; k0 < K; k0 += 32) {
        short8 ah = *(const short8*)(pah + k0);
        short8 al = *(const short8*)(pal + k0);
        short8 bh = *(const short8*)(pbh + k0);
        short8 bl = *(const short8*)(pbl + k0);
        acc = __builtin_amdgcn_mfma_f32_16x16x32_bf16(ah, bh, acc, 0, 0, 0);
        acc = __builtin_amdgcn_mfma_f32_16x16x32_bf16(ah, bl, acc, 0, 0, 0);
        acc = __builtin_amdgcn_mfma_f32_16x16x32_bf16(al, bh, acc, 0, 0, 0);
    }
    int col = c0 + q;
#pragma unroll
    for (int i = 0; i < 4; i++) {
        int row = r0 + g * 4 + i;
        Cf[(size_t)row * N + col] = acc[i];
    }
}

// paired GEMM with rider work. RIDER: 1=scan (block 512); 2=fill (blocks 512..639)
template <int K, int EPI0, int EPI1, int RIDER>
__global__ __launch_bounds__(256) void gemm_pair(
    const ushort* __restrict__ Ah0, const ushort* __restrict__ Al0,
    const ushort* __restrict__ Bh0, const ushort* __restrict__ Bl0,
    const float* __restrict__ bias0, const float* __restrict__ W30,
    float* __restrict__ Cf0, ushort* __restrict__ Oh0, ushort* __restrict__ Ol0,
    const ushort* __restrict__ Ah1, const ushort* __restrict__ Al1,
    const ushort* __restrict__ Bh1, const ushort* __restrict__ Bl1,
    const float* __restrict__ bias1, const float* __restrict__ W31,
    float* __restrict__ Cf1, ushort* __restrict__ Oh1, ushort* __restrict__ Ol1,
    const int* __restrict__ esrc, const int* __restrict__ edst,
    const int* __restrict__ part, int* __restrict__ rowst, int* __restrict__ cursor,
    float* __restrict__ dinv, int* __restrict__ adj) {
    if (RIDER == 1 && blockIdx.x >= 512) {
        __shared__ int ps[256];
        int t = threadIdx.x;
        int d0 = 0, d1 = 0, d2 = 0, d3 = 0;
#pragma unroll
        for (int b = 0; b < 8; b++) {
            int4 qv = *(const int4*)(part + b * 1024 + t * 4);
            d0 += qv.x; d1 += qv.y; d2 += qv.z; d3 += qv.w;
        }
        int sum = d0 + d1 + d2 + d3;
        ps[t] = sum;
        __syncthreads();
        for (int off = 1; off < 256; off <<= 1) {
            int v = (t >= off) ? ps[t - off] : 0;
            __syncthreads();
            ps[t] += v;
            __syncthreads();
        }
        int r0 = ps[t] - sum;
        int r1 = r0 + d0, r2 = r1 + d1, r3 = r2 + d2;
        rowst[t * 4 + 0] = r0;
        rowst[t * 4 + 1] = r1;
        rowst[t * 4 + 2] = r2;
        rowst[t * 4 + 3] = r3;
        if (t == 255) rowst[1024] = r3 + d3;
        cursor[t * 4 + 0] = r0;
        cursor[t * 4 + 1] = r1;
        cursor[t * 4 + 2] = r2;
        cursor[t * 4 + 3] = r3;
        dinv[t * 4 + 0] = d0 > 0 ? rsqrtf((float)d0) : 0.f;
        dinv[t * 4 + 1] = d1 > 0 ? rsqrtf((float)d1) : 0.f;
        dinv[t * 4 + 2] = d2 > 0 ? rsqrtf((float)d2) : 0.f;
        dinv[t * 4 + 3] = d3 > 0 ? rsqrtf((float)d3) : 0.f;
        return;
    }
    if (RIDER == 2 && blockIdx.x >= 512) {
        int e = (blockIdx.x - 512) * 256 + threadIdx.x;
        int d = edst[e];
        int slot = atomicAdd(&cursor[d], 1);
        adj[slot] = esrc[e];
        return;
    }
    int wid = (blockIdx.x * 256 + threadIdx.x) >> 6;
    int lane = threadIdx.x & 63;
    int pair = wid >> 10;
    int widl = wid & 1023;
    int rt = widl & 63, ct = widl >> 6;
    if (pair == 0)
        gemm_wave<K, EPI0>(lane, rt, ct, Ah0, Al0, Bh0, Bl0, bias0, W30, Cf0, Oh0, Ol0, 512);
    else
        gemm_wave<K, EPI1>(lane, rt, ct, Ah1, Al1, Bh1, Bl1, bias1, W31, Cf1, Oh1, Ol1, 512);
}

// =============== aux0 device pieces ===============
__device__ void dev_zero(int sub, int t, float* zbase) {
    for (int i = sub * 256 + t; i < 6144; i += 512) zbase[i] = 0.f;
}

__device__ void dev_tabs_wave(int gw, int lane, const float* __restrict__ class2,
                              const float* __restrict__ wm1, const float* __restrict__ wm2,
                              float* __restrict__ C2s, float* __restrict__ Wm1s,
                              float* __restrict__ Wm2s) {
    if (gw < 2304) {
        float4 v = *(const float4*)(wm1 + (size_t)gw * 256 + lane * 4);
        float s = v.x + v.y + v.z + v.w;
#pragma unroll
        for (int m = 32; m; m >>= 1) s += __shfl_xor(s, m);
        if (lane == 0) Wm1s[gw] = s;
    } else if (gw < 3072) {
        int j = gw - 2304;
        float4 v = *(const float4*)(wm2 + (size_t)j * 256 + lane * 4);
        float s = v.x + v.y + v.z + v.w;
#pragma unroll
        for (int m = 32; m; m >>= 1) s += __shfl_xor(s, m);
        if (lane == 0) Wm2s[j] = s;
    } else {
        int row = (gw - 3072) * 4 + (lane >> 4);
        float4 v = *(const float4*)(class2 + (size_t)row * 64 + (lane & 15) * 4);
        float s = v.x + v.y + v.z + v.w;
#pragma unroll
        for (int m = 8; m; m >>= 1) s += __shfl_xor(s, m);
        if ((lane & 15) == 0) C2s[row] = s;
    }
}

__device__ void dev_splitx(int sub, int t, const float* __restrict__ X,
                           ushort* __restrict__ Xh, ushort* __restrict__ Xl) {
    int j = sub * 256 + t;
    float4 v = ((const float4*)X)[j];
    ushort h0, l0, h1, l1, h2, l2, h3, l3;
    bf16split(v.x, h0, l0);
    bf16split(v.y, h1, l1);
    bf16split(v.z, h2, l2);
    bf16split(v.w, h3, l3);
    ((ushort4*)Xh)[j] = make_ushort4(h0, h1, h2, h3);
    ((ushort4*)Xl)[j] = make_ushort4(l0, l1, l2, l3);
}

__global__ __launch_bounds__(1024) void aux0(
    const float* class2, const float* wm1, const float* wm2,
    float* C2s, float* Wm1s, float* Wm2s, float* zbase,
    const float* x1, ushort* XH1, ushort* XL1,
    const float* x11, ushort* XH2, ushort* XL2,
    const float* W1a, ushort* W1AH, ushort* W1AL,
    const float* W1b, ushort* W1BH, ushort* W1BL,
    const float* W2a, ushort* W2AH, ushort* W2AL,
    const float* W2b, ushort* W2BH, ushort* W2BL,
    const float* G1W, ushort* GWH, ushort* GWL,
    const float* W13, const int* edst, int* part) {
    if (blockIdx.x >= 1017) {
        __shared__ int hist[1024];
        int b = blockIdx.x - 1017;
        int t = threadIdx.x;
        hist[t] = 0;
        __syncthreads();
        const int* ep = edst + b * 4096;
#pragma unroll
        for (int i = 0; i < 4; i++) atomicAdd(&hist[ep[t + i * 1024]], 1);
        __syncthreads();
        part[b * 1024 + t] = hist[t];
        return;
    }
    __shared__ float tb[4][32][33];
    int quad = threadIdx.x >> 8;
    int t = threadIdx.x & 255;
    int sub = blockIdx.x * 4 + quad;
    if (sub >= 4066) return;
    const float* W = nullptr;
    ushort *Th = nullptr, *Tl = nullptr;
    int K = 0, N = 0, tile = 0;
    if (sub >= 3874)      { W = W13; Th = GWH + 256 * 768; Tl = GWL + 256 * 768; K = 768; N = 256; tile = sub - 3874; }
    else if (sub >= 3682) { W = G1W; Th = GWH; Tl = GWL; K = 768; N = 256; tile = sub - 3682; }
    else if (sub >= 3426) { W = W2b; Th = W2BH; Tl = W2BL; K = 512; N = 512; tile = sub - 3426; }
    else if (sub >= 3170) { W = W2a; Th = W2AH; Tl = W2AL; K = 512; N = 512; tile = sub - 3170; }
    else if (sub >= 2786) { W = W1b; Th = W1BH; Tl = W1BL; K = 768; N = 512; tile = sub - 2786; }
    else if (sub >= 2402) { W = W1a; Th = W1AH; Tl = W1AL; K = 768; N = 512; tile = sub - 2402; }
    int k0 = 0, n0 = 0;
    if (W) {
        k0 = (tile % (K / 32)) * 32;
        n0 = (tile / (K / 32)) * 32;
        int tx = t % 32, ty = t / 32;
        for (int i = ty; i < 32; i += 8)
            tb[quad][i][tx] = W[(size_t)(k0 + i) * N + n0 + tx];
    } else if (sub < 2) dev_zero(sub, t, zbase);
    else if (sub < 866) dev_tabs_wave((sub - 2) * 4 + (t >> 6), t & 63,
                                      class2, wm1, wm2, C2s, Wm1s, Wm2s);
    else if (sub < 1634) dev_splitx(sub - 866, t, x1, XH1, XL1);
    else dev_splitx(sub - 1634, t, x11, XH2, XL2);
    __syncthreads();
    if (W) {
        int tx = t % 32, ty = t / 32;
        for (int i = ty; i < 32; i += 8) {
            float v = tb[quad][tx][i];
            ushort h, l;
            bf16split(v, h, l);
            Th[(size_t)(n0 + i) * K + k0 + tx] = h;
            Tl[(size_t)(n0 + i) * K + k0 + tx] = l;
        }
    }
}

// =============== finalize routing + block-local exact repair (R7 verbatim) ===============
__global__ __launch_bounds__(256) void finrep(
    const float* __restrict__ LG, const float* __restrict__ b3, float* __restrict__ rbuf,
    const float* __restrict__ x1, const float* __restrict__ W1, const float* __restrict__ b1,
    const float* __restrict__ W2, const float* __restrict__ b2, const float* __restrict__ W3) {
    __shared__ int snode[4];
    __shared__ int scnt;
    __shared__ float part[4][512];
    __shared__ float xs[768];
    __shared__ float h1[512];
    __shared__ float h2[512];
    int t = threadIdx.x;
    if (t == 0) scnt = 0;
    __syncthreads();
    if (t < 4) {
        int n = blockIdx.x * 4 + t;
        float l0 = LG[n * 4 + 0] + b3[0];
        float l1 = LG[n * 4 + 1] + b3[1];
        float l2 = LG[n * 4 + 2] + b3[2];
        int am = 0;
        float mv = l0;
        if (l1 > mv) { mv = l1; am = 1; }
        if (l2 > mv) { mv = l2; am = 2; }
        float sec = (am == 0) ? fmaxf(l1, l2) : ((am == 1) ? fmaxf(l0, l2) : fmaxf(l0, l1));
        float lo = (1.f - TAU) * 0.5f;
        rbuf[n * 4 + 0] = (am == 0) ? TAU : lo;
        rbuf[n * 4 + 1] = (am == 1) ? TAU : lo;
        rbuf[n * 4 + 2] = (am == 2) ? TAU : lo;
        if (mv - sec < GAPT) {
            int s = atomicAdd(&scnt, 1);
            snode[s] = n;
        }
    }
    __syncthreads();
    int cnt = scnt;
    int w = t >> 6, l = t & 63;
    for (int it = 0; it < cnt; it++) {
        int n = snode[it];
        for (int k = t; k < 768; k += 256) xs[k] = x1[(size_t)n * 768 + k];
        __syncthreads();
        {
            float acc[8] = {0.f, 0.f, 0.f, 0.f, 0.f, 0.f, 0.f, 0.f};
            for (int k = w * 192; k < (w + 1) * 192; k++) {
                float xv = xs[k];
                const float* wr = W1 + (size_t)k * 512 + l;
#pragma unroll
                for (int c = 0; c < 8; c++) acc[c] += xv * wr[64 * c];
            }
#pragma unroll
            for (int c = 0; c < 8; c++) part[w][l + 64 * c] = acc[c];
        }
        __syncthreads();
        for (int d = t; d < 512; d += 256)
            h1[d] = fmaxf(part[0][d] + part[1][d] + part[2][d] + part[3][d] + b1[d], 0.f);
        __syncthreads();
        {
            float acc[8] = {0.f, 0.f, 0.f, 0.f, 0.f, 0.f, 0.f, 0.f};
            for (int k = w * 128; k < (w + 1) * 128; k++) {
                float xv = h1[k];
                const float* wr = W2 + (size_t)k * 512 + l;
#pragma unroll
                for (int c = 0; c < 8; c++) acc[c] += xv * wr[64 * c];
            }
#pragma unroll
            for (int c = 0; c < 8; c++) part[w][l + 64 * c] = acc[c];
        }
        __syncthreads();
        for (int d = t; d < 512; d += 256)
            h2[d] = fmaxf(part[0][d] + part[1][d] + part[2][d] + part[3][d] + b2[d], 0.f);
        __syncthreads();
        if (t < 64) {
            float p0 = 0.f, p1 = 0.f, p2 = 0.f;
            for (int k = t; k < 512; k += 64) {
                float hv = h2[k];
                p0 += hv * W3[k * 3 + 0];
                p1 += hv * W3[k * 3 + 1];
                p2 += hv * W3[k * 3 + 2];
            }
            for (int off = 32; off; off >>= 1) {
                p0 += __shfl_down(p0, off);
                p1 += __shfl_down(p1, off);
                p2 += __shfl_down(p2, off);
            }
            if (t == 0) {
                float l0 = p0 + b3[0], l1 = p1 + b3[1], l2 = p2 + b3[2];
                int am = 0;
                float mv = l0;
                if (l1 > mv) { mv = l1; am = 1; }
                if (l2 > mv) { mv = l2; am = 2; }
                float lo = (1.f - TAU) * 0.5f;
                rbuf[n * 4 + 0] = (am == 0) ? TAU : lo;
                rbuf[n * 4 + 1] = (am == 1) ? TAU : lo;
                rbuf[n * 4 + 2] = (am == 2) ? TAU : lo;
            }
        }
        __syncthreads();
    }
}

// =============== res1 device body (shared by coop phase A and fallback) ===============
__device__ __forceinline__ void res1_body(
    int idx, const float* __restrict__ x2, const float* __restrict__ G,
    const float* __restrict__ m1b3, const float* __restrict__ rbuf,
    const float* __restrict__ C2s, const float* __restrict__ bp1,
    const float* __restrict__ Wm1s, const float* __restrict__ bp2,
    ushort* __restrict__ r1h, ushort* __restrict__ r1l) {
    int n = idx / 192;
    int kq = (idx % 192) * 4;
    float g0 = G[n * 2 + 0] + m1b3[0], g1 = G[n * 2 + 1] + m1b3[1];
    float r0 = rbuf[n * 4 + 0], r1 = rbuf[n * 4 + 1], r2 = rbuf[n * 4 + 2];
    float4 xv = *(const float4*)(x2 + (size_t)n * 768 + kq);
    float4 c0 = *(const float4*)(C2s + kq);
    float4 c1 = *(const float4*)(C2s + 768 + kq);
    float4 p0 = *(const float4*)(bp1 + kq);
    float4 p1 = *(const float4*)(bp1 + 768 + kq);
    float4 w0 = *(const float4*)(Wm1s + kq);
    float4 w1 = *(const float4*)(Wm1s + 768 + kq);
    float4 w2 = *(const float4*)(Wm1s + 1536 + kq);
    float4 q0 = *(const float4*)(bp2 + kq);
    float4 q1 = *(const float4*)(bp2 + 768 + kq);
    float4 q2 = *(const float4*)(bp2 + 1536 + kq);
    float o[4];
    o[0] = (xv.x * (g0 * c0.x + g1 * c1.x) + g0 * p0.x + g1 * p1.x) * (r0 * w0.x + r1 * w1.x + r2 * w2.x) + r0 * q0.x + r1 * q1.x + r2 * q2.x;
    o[1] = (xv.y * (g0 * c0.y + g1 * c1.y) + g0 * p0.y + g1 * p1.y) * (r0 * w0.y + r1 * w1.y + r2 * w2.y) + r0 * q0.y + r1 * q1.y + r2 * q2.y;
    o[2] = (xv.z * (g0 * c0.z + g1 * c1.z) + g0 * p0.z + g1 * p1.z) * (r0 * w0.z + r1 * w1.z + r2 * w2.z) + r0 * q0.z + r1 * q1.z + r2 * q2.z;
    o[3] = (xv.w * (g0 * c0.w + g1 * c1.w) + g0 * p0.w + g1 * p1.w) * (r0 * w0.w + r1 * w1.w + r2 * w2.w) + r0 * q0.w + r1 * q1.w + r2 * q2.w;
    ushort hh[4], ll[4];
#pragma unroll
    for (int i = 0; i < 4; i++) bf16split(o[i], hh[i], ll[i]);
    size_t off = ((size_t)n * 768 + kq) / 4;
    ((ushort4*)r1h)[off] = make_ushort4(hh[0], hh[1], hh[2], hh[3]);
    ((ushort4*)r1l)[off] = make_ushort4(ll[0], ll[1], ll[2], ll[3]);
}

__global__ __launch_bounds__(256) void res1_kernel(
    const float* __restrict__ x2, const float* __restrict__ G, const float* __restrict__ m1b3,
    const float* __restrict__ rbuf, const float* __restrict__ C2s, const float* __restrict__ bp1,
    const float* __restrict__ Wm1s, const float* __restrict__ bp2,
    ushort* __restrict__ r1h, ushort* __restrict__ r1l) {
    res1_body(blockIdx.x * 256 + threadIdx.x, x2, G, m1b3, rbuf, C2s, bp1, Wm1s, bp2, r1h, r1l);
}

// =============== gather phase bodies (shared) ===============
__device__ __forceinline__ void gather1_body(
    int n, int t, const float* __restrict__ gcw, const int* __restrict__ rowst,
    const int* __restrict__ adj, const float* __restrict__ dinv,
    const float* __restrict__ gcn1_b, const float* __restrict__ rbuf,
    const float* __restrict__ wm12, const float* __restrict__ Wm2s,
    float* __restrict__ res2f) {
    int k = t;
    int lane = t & 63;
    int e0 = rowst[n], e1 = rowst[n + 1];
    float acc = 0.f;
    for (int base = e0; base < e1; base += 64) {
        int idx = base + lane;
        int s_i = 0;
        float w_i = 0.f;
        if (idx < e1) { s_i = adj[idx]; w_i = dinv[s_i]; }
        int mm = min(64, e1 - base);
        for (int j = 0; j < mm; j++) {
            int s = __shfl(s_i, j);
            float w = __shfl(w_i, j);
            acc += gcw[(size_t)s * 512 + k] * w;
        }
    }
    float h1v = dinv[n] * acc + gcn1_b[k];
    float mv = gcw[(size_t)n * 512 + 256 + k];
    float r0 = rbuf[n * 4 + 0], r1 = rbuf[n * 4 + 1], r2 = rbuf[n * 4 + 2];
    float a = r0 * wm12[k] + r1 * wm12[256 + k] + r2 * wm12[512 + k];
    float w = r0 * Wm2s[k] + r1 * Wm2s[256 + k] + r2 * Wm2s[512 + k];
    res2f[(size_t)n * 256 + k] = w * (a * fmaxf(h1v, 0.f) + 2e-4f * mv);
}

__global__ __launch_bounds__(256) void gather1_combine(
    const float* __restrict__ gcw, const int* __restrict__ rowst, const int* __restrict__ adj,
    const float* __restrict__ dinv, const float* __restrict__ gcn1_b,
    const float* __restrict__ rbuf, const float* __restrict__ wm12,
    const float* __restrict__ Wm2s, float* __restrict__ res2f) {
    gather1_body(blockIdx.x, threadIdx.x, gcw, rowst, adj, dinv, gcn1_b, rbuf, wm12, Wm2s, res2f);
}

__device__ __forceinline__ void gather2_body(
    int n, int t, float* gres, float (*part)[32],
    const float* __restrict__ res2f, const int* __restrict__ rowst,
    const int* __restrict__ adj, const float* __restrict__ dinv,
    const float* __restrict__ G2W, const float* __restrict__ gcn2_b,
    const float* __restrict__ fcW, const float* __restrict__ fcb,
    float* __restrict__ out) {
    int lane = t & 63;
    int e0 = rowst[n], e1 = rowst[n + 1];
    float acc = 0.f;
    for (int base = e0; base < e1; base += 64) {
        int idx = base + lane;
        int s_i = 0;
        float w_i = 0.f;
        if (idx < e1) { s_i = adj[idx]; w_i = dinv[s_i]; }
        int mm = min(64, e1 - base);
        for (int j = 0; j < mm; j++) {
            int s = __shfl(s_i, j);
            float w = __shfl(w_i, j);
            acc += res2f[(size_t)s * 256 + t] * w;
        }
    }
    gres[t] = acc * dinv[n];
    __syncthreads();
    int j = t & 31, seg = t >> 5;
    float p = 0.f;
#pragma unroll
    for (int kk = 0; kk < 32; kk++) {
        int k = seg * 32 + kk;
        p += gres[k] * G2W[k * 32 + j];
    }
    part[seg][j] = p;
    __syncthreads();
    if (t < 32) {
        float h2v = part[0][t] + part[1][t] + part[2][t] + part[3][t] +
                    part[4][t] + part[5][t] + part[6][t] + part[7][t] + gcn2_b[t];
        gres[t] = fmaxf(h2v, 0.f);
    }
    __syncthreads();
    if (t < 8) {
        float logit = fcb[t];
#pragma unroll
        for (int i = 0; i < 32; i++) logit += gres[i] * fcW[i * 8 + t];
        float m = logit;
        for (int off = 4; off; off >>= 1) m = fmaxf(m, __shfl_xor(m, off, 8));
        float e = expf(logit - m), s = e;
        for (int off = 4; off; off >>= 1) s += __shfl_xor(s, off, 8);
        out[(size_t)n * 8 + t] = logit - m - logf(s);
    }
    __syncthreads();
}

__global__ __launch_bounds__(256) void gather2_full(
    const float* __restrict__ res2f, const int* __restrict__ rowst,
    const int* __restrict__ adj, const float* __restrict__ dinv,
    const float* __restrict__ G2W, const float* __restrict__ gcn2_b,
    const float* __restrict__ fcW, const float* __restrict__ fcb,
    float* __restrict__ out) {
    __shared__ float gres[256];
    __shared__ float part[8][32];
    gather2_body(blockIdx.x, threadIdx.x, gres, part, res2f, rowst, adj, dinv,
                 G2W, gcn2_b, fcW, fcb, out);
}

// =============== cooperative tail (grid-stride, any grid size) ===============
__global__ __launch_bounds__(256) void tail_coop(
    const float* __restrict__ x2, const float* __restrict__ G, const float* __restrict__ m1b3,
    const float* __restrict__ rbuf, const float* __restrict__ C2s, const float* __restrict__ bp1,
    const float* __restrict__ Wm1s, const float* __restrict__ bp2,
    ushort* __restrict__ r1h, ushort* __restrict__ r1l,
    const ushort* __restrict__ GWH, const ushort* __restrict__ GWL,
    float* __restrict__ gcw,
    const int* __restrict__ rowst, const int* __restrict__ adj, const float* __restrict__ dinv,
    const float* __restrict__ gcn1_b, const float* __restrict__ wm12,
    const float* __restrict__ Wm2s, float* __restrict__ res2f,
    const float* __restrict__ G2W, const float* __restrict__ gcn2_b,
    const float* __restrict__ fcW, const float* __restrict__ fcb, float* __restrict__ out) {
    cg::grid_group gg = cg::this_grid();
    int t = threadIdx.x;
    int nthreads = gridDim.x * 256;

    // phase A: res1 (196608 quads)
    for (int idx = blockIdx.x * 256 + t; idx < 196608; idx += nthreads)
        res1_body(idx, x2, G, m1b3, rbuf, C2s, bp1, Wm1s, bp2, r1h, r1l);
    gg.sync();

    // phase B: gcw = res1 @ [gcn1_W | wm13] (2048 wave jobs of 16x16)
    {
        int totwaves = gridDim.x * 4;
        int lane = t & 63;
        for (int wid = (blockIdx.x * 256 + t) >> 6; wid < 2048; wid += totwaves) {
            constexpr int K = 768, Nn = 512;
            int rt = wid & 63, ct = wid >> 6;
            int r0 = rt * 16, c0 = ct * 16;
            int g = lane >> 4, q = lane & 15;
            const ushort* pah = r1h + (size_t)(r0 + q) * K + g * 8;
            const ushort* pal = r1l + (size_t)(r0 + q) * K + g * 8;
            const ushort* pbh = GWH + (size_t)(c0 + q) * K + g * 8;
            const ushort* pbl = GWL + (size_t)(c0 + q) * K + g * 8;
            f32x4 acc = {0.f, 0.f, 0.f, 0.f};
#pragma unroll 2
            for (int k0 = 0; k0 < K; k0 += 32) {
                short8 ah = *(const short8*)(pah + k0);
                short8 al = *(const short8*)(pal + k0);
                short8 bh = *(const short8*)(pbh + k0);
                short8 bl = *(const short8*)(pbl + k0);
                acc = __builtin_amdgcn_mfma_f32_16x16x32_bf16(ah, bh, acc, 0, 0, 0);
                acc = __builtin_amdgcn_mfma_f32_16x16x32_bf16(ah, bl, acc, 0, 0, 0);
                acc = __builtin_amdgcn_mfma_f32_16x16x32_bf16(al, bh, acc, 0, 0, 0);
            }
            int col = c0 + q;
#pragma unroll
            for (int i = 0; i < 4; i++) {
                int row = r0 + g * 4 + i;
                gcw[(size_t)row * Nn + col] = acc[i];
            }
        }
    }
    gg.sync();

    // phase C: gather1 + combine
    for (int n = blockIdx.x; n < NN; n += gridDim.x)
        gather1_body(n, t, gcw, rowst, adj, dinv, gcn1_b, rbuf, wm12, Wm2s, res2f);
    gg.sync();

    // phase D: gather2 + fc + log_softmax
    {
        __shared__ float gres[256];
        __shared__ float part[8][32];
        for (int n = blockIdx.x; n < NN; n += gridDim.x)
            gather2_body(n, t, gres, part, res2f, rowst, adj, dinv, G2W, gcn2_b, fcW, fcb, out);
    }
}

extern "C" void kernel_launch(void* const* d_in, const int* in_sizes, int n_in,
                              void* d_out, int out_size, void* d_ws, size_t ws_size,
                              hipStream_t stream) {
    const float* x1     = (const float*)d_in[0];
    const float* x11    = (const float*)d_in[1];
    const float* x2     = (const float*)d_in[2];
    const float* mlp_W1 = (const float*)d_in[3];
    const float* mlp_b1 = (const float*)d_in[4];
    const float* mlp_W2 = (const float*)d_in[5];
    const float* mlp_b2 = (const float*)d_in[6];
    const float* mlp_W3 = (const float*)d_in[7];
    const float* mlp_b3 = (const float*)d_in[8];
    const float* m1_W1  = (const float*)d_in[9];
    const float* m1_b1  = (const float*)d_in[10];
    const float* m1_W2  = (const float*)d_in[11];
    const float* m1_b2  = (const float*)d_in[12];
    const float* m1_W3  = (const float*)d_in[13];
    const float* m1_b3  = (const float*)d_in[14];
    const float* wm1    = (const float*)d_in[15];
    const float* bp1    = (const float*)d_in[16];
    const float* bp2    = (const float*)d_in[17];
    const float* wm12   = (const float*)d_in[18];
    const float* wm13   = (const float*)d_in[19];
    const float* class2 = (const float*)d_in[20];
    const float* gcn1_W = (const float*)d_in[21];
    const float* gcn1_b = (const float*)d_in[22];
    const float* wm2    = (const float*)d_in[23];
    const float* gcn2_W = (const float*)d_in[24];
    const float* gcn2_b = (const float*)d_in[25];
    const float* fc_W   = (const float*)d_in[26];
    const float* fc_b   = (const float*)d_in[27];
    const int* eidx     = (const int*)d_in[28];
    const int* esrc = eidx;
    const int* edst = eidx + NE;

    char* ws = (char*)d_ws;
    ushort* XH1   = (ushort*)(ws + 0x0000000);
    ushort* XL1   = (ushort*)(ws + 0x0180000);
    ushort* XH2   = (ushort*)(ws + 0x0300000);
    ushort* XL2   = (ushort*)(ws + 0x0480000);
    ushort* W1AH  = (ushort*)(ws + 0x0600000);
    ushort* W1AL  = (ushort*)(ws + 0x06C0000);
    ushort* W1BH  = (ushort*)(ws + 0x0780000);
    ushort* W1BL  = (ushort*)(ws + 0x0840000);
    ushort* W2AH  = (ushort*)(ws + 0x0900000);
    ushort* W2AL  = (ushort*)(ws + 0x0980000);
    ushort* W2BH  = (ushort*)(ws + 0x0A00000);
    ushort* W2BL  = (ushort*)(ws + 0x0A80000);
    ushort* GWH   = (ushort*)(ws + 0x0B00000);
    ushort* GWL   = (ushort*)(ws + 0x0BC0000);
    ushort* HS1AH = (ushort*)(ws + 0x0D00000);
    ushort* HS1AL = (ushort*)(ws + 0x0E00000);
    ushort* HS1BH = (ushort*)(ws + 0x0F00000);
    ushort* HS1BL = (ushort*)(ws + 0x1000000);
    ushort* RES1H = (ushort*)(ws + 0x1100000);
    ushort* RES1L = (ushort*)(ws + 0x1280000);
    float*  GCW   = (float*)(ws + 0x1400000);
    float*  RES2F = (float*)(ws + 0x1600000);
    float* LOGITS = (float*)(ws + 0x1740000);
    float* GBUF   = (float*)(ws + 0x1744000);
    float* RBUF   = (float*)(ws + 0x1746000);
    float* DINV   = (float*)(ws + 0x174A000);
    int*   ROWST  = (int*)(ws + 0x174B000);
    int*   CURS   = (int*)(ws + 0x174D000);
    int*   ADJ    = (int*)(ws + 0x174E000);
    float* C2S    = (float*)(ws + 0x1770000);
    float* WM1S   = (float*)(ws + 0x1772000);
    float* WM2S   = (float*)(ws + 0x1775000);
    int*   PART   = (int*)(ws + 0x1780000);

    // D0: prep + LDS-hist degree count
    aux0<<<1025, 1024, 0, stream>>>(class2, wm1, wm2, C2S, WM1S, WM2S, LOGITS,
                                    x1, XH1, XL1, x11, XH2, XL2,
                                    mlp_W1, W1AH, W1AL, m1_W1, W1BH, W1BL,
                                    mlp_W2, W2AH, W2AL, m1_W2, W2BH, W2BL,
                                    gcn1_W, GWH, GWL, wm13, edst, PART);
    // D1: L1 pair + CSR scan rider
    gemm_pair<768, 1, 1, 1><<<513, 256, 0, stream>>>(
        XH1, XL1, W1AH, W1AL, mlp_b1, nullptr, nullptr, HS1AH, HS1AL,
        XH2, XL2, W1BH, W1BL, m1_b1, nullptr, nullptr, HS1BH, HS1BL,
        esrc, edst, PART, ROWST, CURS, DINV, ADJ);
    // D2: L2 pair + adj-fill riders
    gemm_pair<512, 2, 3, 2><<<640, 256, 0, stream>>>(
        HS1AH, HS1AL, W2AH, W2AL, mlp_b2, mlp_W3, LOGITS, nullptr, nullptr,
        HS1BH, HS1BL, W2BH, W2BL, m1_b2, m1_W3, GBUF, nullptr, nullptr,
        esrc, edst, PART, ROWST, CURS, DINV, ADJ);
    // D3: finalize + repair
    finrep<<<256, 256, 0, stream>>>(LOGITS, mlp_b3, RBUF, x1, mlp_W1, mlp_b1,
                                    mlp_W2, mlp_b2, mlp_W3);

    // D4: cooperative tail, capacity-checked with fallback to 4 kernels
    hipError_t lerr = hipErrorUnknown;
    int occ = 0;
    if (hipOccupancyMaxActiveBlocksPerMultiprocessor(&occ, tail_coop, 256, 0) == hipSuccess &&
        occ >= 1) {
        int nb = occ * 256;              // 256 CUs on MI355X
        if (nb > 1024) nb = 1024;
        float* outp = (float*)d_out;
        const float* m1b3p = m1_b3;
        void* args[] = {
            (void*)&x2, (void*)&GBUF, (void*)&m1b3p, (void*)&RBUF, (void*)&C2S,
            (void*)&bp1, (void*)&WM1S, (void*)&bp2, (void*)&RES1H, (void*)&RES1L,
            (void*)&GWH, (void*)&GWL, (void*)&GCW, (void*)&ROWST, (void*)&ADJ,
            (void*)&DINV, (void*)&gcn1_b, (void*)&wm12, (void*)&WM2S, (void*)&RES2F,
            (void*)&gcn2_W, (void*)&gcn2_b, (void*)&fc_W, (void*)&fc_b, (void*)&outp};
        lerr = hipLaunchCooperativeKernel((const void*)tail_coop, dim3(nb), dim3(256),
                                          args, 0, stream);
    }
    if (lerr != hipSuccess) {
        // fallback: R10-proven 4-dispatch tail
        res1_kernel<<<768, 256, 0, stream>>>(x2, GBUF, m1_b3, RBUF, C2S, bp1, WM1S, bp2,
                                             RES1H, RES1L);
        gemm3_n16<1024, 512, 768><<<512, 256, 0, stream>>>(RES1H, RES1L, GWH, GWL, GCW);
        gather1_combine<<<NN, 256, 0, stream>>>(GCW, ROWST, ADJ, DINV, gcn1_b, RBUF,
                                                wm12, WM2S, RES2F);
        gather2_full<<<NN, 256, 0, stream>>>(RES2F, ROWST, ADJ, DINV, gcn2_W, gcn2_b,
                                             fc_W, fc_b, (float*)d_out);
    }
}

// Round 13
// 165.110 us; speedup vs baseline: 2.0894x; 2.0894x over previous
//
#include <hip/hip_runtime.h>
#include <hip/hip_bf16.h>

#define NN 1024
#define NE 32768
#define TAU 0.7f
#define GAPT 0.01f

typedef __attribute__((ext_vector_type(8))) short short8;
typedef __attribute__((ext_vector_type(4))) float f32x4;

__device__ inline ushort bf16rne(float x) {
    union { float f; unsigned u; } a; a.f = x;
    unsigned r = (a.u + 0x7FFFu + ((a.u >> 16) & 1u)) >> 16;
    return (ushort)r;
}
__device__ inline float bf16tof(ushort h) {
    union { unsigned u; float f; } a; a.u = ((unsigned)h) << 16;
    return a.f;
}
__device__ inline void bf16split(float x, ushort& h, ushort& l) {
    h = bf16rne(x);
    l = bf16rne(x - bf16tof(h));
}

// =============== bf16x3 MFMA wave job: 16 rows x 32 cols, full K ===============
template <int K, int EPI>
__device__ __forceinline__ void gemm_wave(
    int lane, int rt, int ct,
    const ushort* __restrict__ Ah, const ushort* __restrict__ Al,
    const ushort* __restrict__ Bh, const ushort* __restrict__ Bl,
    const float* __restrict__ bias, const float* __restrict__ W3,
    float* __restrict__ Cf, ushort* __restrict__ Oh, ushort* __restrict__ Ol, int N) {
    int r0 = rt * 16, c0 = ct * 32;
    int g = lane >> 4, q = lane & 15;
    const ushort* pah = Ah + (size_t)(r0 + q) * K + g * 8;
    const ushort* pal = Al + (size_t)(r0 + q) * K + g * 8;
    const ushort* pb0h = Bh + (size_t)(c0 + q) * K + g * 8;
    const ushort* pb0l = Bl + (size_t)(c0 + q) * K + g * 8;
    const ushort* pb1h = pb0h + (size_t)16 * K;
    const ushort* pb1l = pb0l + (size_t)16 * K;
    f32x4 acc0 = {0.f, 0.f, 0.f, 0.f};
    f32x4 acc1 = {0.f, 0.f, 0.f, 0.f};
#pragma unroll 2
    for (int k0 = 0; k0 < K; k0 += 32) {
        short8 ah = *(const short8*)(pah + k0);
        short8 al = *(const short8*)(pal + k0);
        short8 b0h = *(const short8*)(pb0h + k0);
        short8 b0l = *(const short8*)(pb0l + k0);
        short8 b1h = *(const short8*)(pb1h + k0);
        short8 b1l = *(const short8*)(pb1l + k0);
        acc0 = __builtin_amdgcn_mfma_f32_16x16x32_bf16(ah, b0h, acc0, 0, 0, 0);
        acc1 = __builtin_amdgcn_mfma_f32_16x16x32_bf16(ah, b1h, acc1, 0, 0, 0);
        acc0 = __builtin_amdgcn_mfma_f32_16x16x32_bf16(ah, b0l, acc0, 0, 0, 0);
        acc1 = __builtin_amdgcn_mfma_f32_16x16x32_bf16(ah, b1l, acc1, 0, 0, 0);
        acc0 = __builtin_amdgcn_mfma_f32_16x16x32_bf16(al, b0h, acc0, 0, 0, 0);
        acc1 = __builtin_amdgcn_mfma_f32_16x16x32_bf16(al, b1h, acc1, 0, 0, 0);
    }
    int col0 = c0 + q, col1 = c0 + 16 + q;
    if constexpr (EPI == 0) {
#pragma unroll
        for (int i = 0; i < 4; i++) {
            int row = r0 + g * 4 + i;
            Cf[(size_t)row * N + col0] = acc0[i];
            Cf[(size_t)row * N + col1] = acc1[i];
        }
    } else if constexpr (EPI == 1) {
        float bv0 = bias[col0], bv1 = bias[col1];
#pragma unroll
        for (int i = 0; i < 4; i++) {
            int row = r0 + g * 4 + i;
            float a0 = fmaxf(acc0[i] + bv0, 0.f);
            float a1 = fmaxf(acc1[i] + bv1, 0.f);
            ushort h, l;
            bf16split(a0, h, l);
            Oh[(size_t)row * N + col0] = h;
            Ol[(size_t)row * N + col0] = l;
            bf16split(a1, h, l);
            Oh[(size_t)row * N + col1] = h;
            Ol[(size_t)row * N + col1] = l;
        }
    } else {
        constexpr int J = (EPI == 2) ? 3 : 2;
        constexpr int STR = (EPI == 2) ? 4 : 2;
        float bv0 = bias[col0], bv1 = bias[col1];
        float s[4][J];
#pragma unroll
        for (int i = 0; i < 4; i++) {
            float a0 = fmaxf(acc0[i] + bv0, 0.f);
            float a1 = fmaxf(acc1[i] + bv1, 0.f);
#pragma unroll
            for (int j = 0; j < J; j++)
                s[i][j] = a0 * W3[col0 * J + j] + a1 * W3[col1 * J + j];
        }
#pragma unroll
        for (int i = 0; i < 4; i++)
#pragma unroll
            for (int j = 0; j < J; j++) {
                float v = s[i][j];
#pragma unroll
                for (int m = 1; m < 16; m <<= 1) v += __shfl_xor(v, m);
                s[i][j] = v;
            }
        if (q == 0) {
#pragma unroll
            for (int i = 0; i < 4; i++) {
                int row = r0 + g * 4 + i;
#pragma unroll
                for (int j = 0; j < J; j++) atomicAdd(&Cf[(size_t)row * STR + j], s[i][j]);
            }
        }
    }
}

// 16-col variant: 3 MFMA per k-step, 2x the waves (latency hiding for D5)
template <int M, int N, int K>
__global__ __launch_bounds__(256) void gemm3_n16(
    const ushort* __restrict__ Ah, const ushort* __restrict__ Al,
    const ushort* __restrict__ Bh, const ushort* __restrict__ Bl,
    float* __restrict__ Cf) {
    constexpr int RT = M / 16;
    constexpr int JOBS = RT * (N / 16);
    int wid = (blockIdx.x * 256 + threadIdx.x) >> 6;
    if (wid >= JOBS) return;
    int lane = threadIdx.x & 63;
    int rt = wid % RT, ct = wid / RT;
    int r0 = rt * 16, c0 = ct * 16;
    int g = lane >> 4, q = lane & 15;
    const ushort* pah = Ah + (size_t)(r0 + q) * K + g * 8;
    const ushort* pal = Al + (size_t)(r0 + q) * K + g * 8;
    const ushort* pbh = Bh + (size_t)(c0 + q) * K + g * 8;
    const ushort* pbl = Bl + (size_t)(c0 + q) * K + g * 8;
    f32x4 acc = {0.f, 0.f, 0.f, 0.f};
#pragma unroll 2
    for (int k0 = 0; k0 < K; k0 += 32) {
        short8 ah = *(const short8*)(pah + k0);
        short8 al = *(const short8*)(pal + k0);
        short8 bh = *(const short8*)(pbh + k0);
        short8 bl = *(const short8*)(pbl + k0);
        acc = __builtin_amdgcn_mfma_f32_16x16x32_bf16(ah, bh, acc, 0, 0, 0);
        acc = __builtin_amdgcn_mfma_f32_16x16x32_bf16(ah, bl, acc, 0, 0, 0);
        acc = __builtin_amdgcn_mfma_f32_16x16x32_bf16(al, bh, acc, 0, 0, 0);
    }
    int col = c0 + q;
#pragma unroll
    for (int i = 0; i < 4; i++) {
        int row = r0 + g * 4 + i;
        Cf[(size_t)row * N + col] = acc[i];
    }
}

// paired GEMM with rider work. RIDER: 1=scan (block 512); 2=fill (blocks 512..639)
template <int K, int EPI0, int EPI1, int RIDER>
__global__ __launch_bounds__(256) void gemm_pair(
    const ushort* __restrict__ Ah0, const ushort* __restrict__ Al0,
    const ushort* __restrict__ Bh0, const ushort* __restrict__ Bl0,
    const float* __restrict__ bias0, const float* __restrict__ W30,
    float* __restrict__ Cf0, ushort* __restrict__ Oh0, ushort* __restrict__ Ol0,
    const ushort* __restrict__ Ah1, const ushort* __restrict__ Al1,
    const ushort* __restrict__ Bh1, const ushort* __restrict__ Bl1,
    const float* __restrict__ bias1, const float* __restrict__ W31,
    float* __restrict__ Cf1, ushort* __restrict__ Oh1, ushort* __restrict__ Ol1,
    const int* __restrict__ esrc, const int* __restrict__ edst,
    const int* __restrict__ part, int* __restrict__ rowst, int* __restrict__ cursor,
    float* __restrict__ dinv, int* __restrict__ adj) {
    if (RIDER == 1 && blockIdx.x >= 512) {
        // CSR scan from 8 partial histograms, 4 nodes/thread
        __shared__ int ps[256];
        int t = threadIdx.x;
        int d0 = 0, d1 = 0, d2 = 0, d3 = 0;
#pragma unroll
        for (int b = 0; b < 8; b++) {
            int4 qv = *(const int4*)(part + b * 1024 + t * 4);
            d0 += qv.x; d1 += qv.y; d2 += qv.z; d3 += qv.w;
        }
        int sum = d0 + d1 + d2 + d3;
        ps[t] = sum;
        __syncthreads();
        for (int off = 1; off < 256; off <<= 1) {
            int v = (t >= off) ? ps[t - off] : 0;
            __syncthreads();
            ps[t] += v;
            __syncthreads();
        }
        int r0 = ps[t] - sum;
        int r1 = r0 + d0, r2 = r1 + d1, r3 = r2 + d2;
        rowst[t * 4 + 0] = r0;
        rowst[t * 4 + 1] = r1;
        rowst[t * 4 + 2] = r2;
        rowst[t * 4 + 3] = r3;
        if (t == 255) rowst[1024] = r3 + d3;
        cursor[t * 4 + 0] = r0;
        cursor[t * 4 + 1] = r1;
        cursor[t * 4 + 2] = r2;
        cursor[t * 4 + 3] = r3;
        dinv[t * 4 + 0] = d0 > 0 ? rsqrtf((float)d0) : 0.f;
        dinv[t * 4 + 1] = d1 > 0 ? rsqrtf((float)d1) : 0.f;
        dinv[t * 4 + 2] = d2 > 0 ? rsqrtf((float)d2) : 0.f;
        dinv[t * 4 + 3] = d3 > 0 ? rsqrtf((float)d3) : 0.f;
        return;
    }
    if (RIDER == 2 && blockIdx.x >= 512) {
        int e = (blockIdx.x - 512) * 256 + threadIdx.x;
        int d = edst[e];
        int slot = atomicAdd(&cursor[d], 1);
        adj[slot] = esrc[e];
        return;
    }
    int wid = (blockIdx.x * 256 + threadIdx.x) >> 6;
    int lane = threadIdx.x & 63;
    int pair = wid >> 10;
    int widl = wid & 1023;
    int rt = widl & 63, ct = widl >> 6;
    if (pair == 0)
        gemm_wave<K, EPI0>(lane, rt, ct, Ah0, Al0, Bh0, Bl0, bias0, W30, Cf0, Oh0, Ol0, 512);
    else
        gemm_wave<K, EPI1>(lane, rt, ct, Ah1, Al1, Bh1, Bl1, bias1, W31, Cf1, Oh1, Ol1, 512);
}

// =============== aux0 device pieces ===============
__device__ void dev_zero(int sub, int t, float* zbase) {
    for (int i = sub * 256 + t; i < 6144; i += 512) zbase[i] = 0.f;
}

__device__ void dev_tabs_wave(int gw, int lane, const float* __restrict__ class2,
                              const float* __restrict__ wm1, const float* __restrict__ wm2,
                              float* __restrict__ C2s, float* __restrict__ Wm1s,
                              float* __restrict__ Wm2s) {
    if (gw < 2304) {
        float4 v = *(const float4*)(wm1 + (size_t)gw * 256 + lane * 4);
        float s = v.x + v.y + v.z + v.w;
#pragma unroll
        for (int m = 32; m; m >>= 1) s += __shfl_xor(s, m);
        if (lane == 0) Wm1s[gw] = s;
    } else if (gw < 3072) {
        int j = gw - 2304;
        float4 v = *(const float4*)(wm2 + (size_t)j * 256 + lane * 4);
        float s = v.x + v.y + v.z + v.w;
#pragma unroll
        for (int m = 32; m; m >>= 1) s += __shfl_xor(s, m);
        if (lane == 0) Wm2s[j] = s;
    } else {
        int row = (gw - 3072) * 4 + (lane >> 4);
        float4 v = *(const float4*)(class2 + (size_t)row * 64 + (lane & 15) * 4);
        float s = v.x + v.y + v.z + v.w;
#pragma unroll
        for (int m = 8; m; m >>= 1) s += __shfl_xor(s, m);
        if ((lane & 15) == 0) C2s[row] = s;
    }
}

__device__ void dev_splitx(int sub, int t, const float* __restrict__ X,
                           ushort* __restrict__ Xh, ushort* __restrict__ Xl) {
    int j = sub * 256 + t;
    float4 v = ((const float4*)X)[j];
    ushort h0, l0, h1, l1, h2, l2, h3, l3;
    bf16split(v.x, h0, l0);
    bf16split(v.y, h1, l1);
    bf16split(v.z, h2, l2);
    bf16split(v.w, h3, l3);
    ((ushort4*)Xh)[j] = make_ushort4(h0, h1, h2, h3);
    ((ushort4*)Xl)[j] = make_ushort4(l0, l1, l2, l3);
}

// sub layout: [0,2) zero | [2,866) tabs | [866,1634) x1 | [1634,2402) x11 |
// [2402,2786) W1a | [2786,3170) W1b | [3170,3426) W2a | [3426,3682) W2b |
// [3682,3874) G1W | [3874,4066) W13.   Blocks >= 1017: LDS-hist degree count.
__global__ __launch_bounds__(1024) void aux0(
    const float* class2, const float* wm1, const float* wm2,
    float* C2s, float* Wm1s, float* Wm2s, float* zbase,
    const float* x1, ushort* XH1, ushort* XL1,
    const float* x11, ushort* XH2, ushort* XL2,
    const float* W1a, ushort* W1AH, ushort* W1AL,
    const float* W1b, ushort* W1BH, ushort* W1BL,
    const float* W2a, ushort* W2AH, ushort* W2AL,
    const float* W2b, ushort* W2BH, ushort* W2BL,
    const float* G1W, ushort* GWH, ushort* GWL,
    const float* W13, const int* edst, int* part) {
    if (blockIdx.x >= 1017) {
        // degree count: 8 blocks x 4096 edges -> PART[b][1024] (write, no global zero)
        __shared__ int hist[1024];
        int b = blockIdx.x - 1017;
        int t = threadIdx.x;
        hist[t] = 0;
        __syncthreads();
        const int* ep = edst + b * 4096;
#pragma unroll
        for (int i = 0; i < 4; i++) atomicAdd(&hist[ep[t + i * 1024]], 1);
        __syncthreads();
        part[b * 1024 + t] = hist[t];
        return;
    }
    __shared__ float tb[4][32][33];
    int quad = threadIdx.x >> 8;
    int t = threadIdx.x & 255;
    int sub = blockIdx.x * 4 + quad;
    if (sub >= 4066) return;
    const float* W = nullptr;
    ushort *Th = nullptr, *Tl = nullptr;
    int K = 0, N = 0, tile = 0;
    if (sub >= 3874)      { W = W13; Th = GWH + 256 * 768; Tl = GWL + 256 * 768; K = 768; N = 256; tile = sub - 3874; }
    else if (sub >= 3682) { W = G1W; Th = GWH; Tl = GWL; K = 768; N = 256; tile = sub - 3682; }
    else if (sub >= 3426) { W = W2b; Th = W2BH; Tl = W2BL; K = 512; N = 512; tile = sub - 3426; }
    else if (sub >= 3170) { W = W2a; Th = W2AH; Tl = W2AL; K = 512; N = 512; tile = sub - 3170; }
    else if (sub >= 2786) { W = W1b; Th = W1BH; Tl = W1BL; K = 768; N = 512; tile = sub - 2786; }
    else if (sub >= 2402) { W = W1a; Th = W1AH; Tl = W1AL; K = 768; N = 512; tile = sub - 2402; }
    int k0 = 0, n0 = 0;
    if (W) {
        k0 = (tile % (K / 32)) * 32;
        n0 = (tile / (K / 32)) * 32;
        int tx = t % 32, ty = t / 32;
        for (int i = ty; i < 32; i += 8)
            tb[quad][i][tx] = W[(size_t)(k0 + i) * N + n0 + tx];
    } else if (sub < 2) dev_zero(sub, t, zbase);
    else if (sub < 866) dev_tabs_wave((sub - 2) * 4 + (t >> 6), t & 63,
                                      class2, wm1, wm2, C2s, Wm1s, Wm2s);
    else if (sub < 1634) dev_splitx(sub - 866, t, x1, XH1, XL1);
    else dev_splitx(sub - 1634, t, x11, XH2, XL2);
    __syncthreads();
    if (W) {
        int tx = t % 32, ty = t / 32;
        for (int i = ty; i < 32; i += 8) {
            float v = tb[quad][tx][i];
            ushort h, l;
            bf16split(v, h, l);
            Th[(size_t)(n0 + i) * K + k0 + tx] = h;
            Tl[(size_t)(n0 + i) * K + k0 + tx] = l;
        }
    }
}

// =============== finalize routing + block-local exact repair (R7 verbatim) ===============
__global__ __launch_bounds__(256) void finrep(
    const float* __restrict__ LG, const float* __restrict__ b3, float* __restrict__ rbuf,
    const float* __restrict__ x1, const float* __restrict__ W1, const float* __restrict__ b1,
    const float* __restrict__ W2, const float* __restrict__ b2, const float* __restrict__ W3) {
    __shared__ int snode[4];
    __shared__ int scnt;
    __shared__ float part[4][512];
    __shared__ float xs[768];
    __shared__ float h1[512];
    __shared__ float h2[512];
    int t = threadIdx.x;
    if (t == 0) scnt = 0;
    __syncthreads();
    if (t < 4) {
        int n = blockIdx.x * 4 + t;
        float l0 = LG[n * 4 + 0] + b3[0];
        float l1 = LG[n * 4 + 1] + b3[1];
        float l2 = LG[n * 4 + 2] + b3[2];
        int am = 0;
        float mv = l0;
        if (l1 > mv) { mv = l1; am = 1; }
        if (l2 > mv) { mv = l2; am = 2; }
        float sec = (am == 0) ? fmaxf(l1, l2) : ((am == 1) ? fmaxf(l0, l2) : fmaxf(l0, l1));
        float lo = (1.f - TAU) * 0.5f;
        rbuf[n * 4 + 0] = (am == 0) ? TAU : lo;
        rbuf[n * 4 + 1] = (am == 1) ? TAU : lo;
        rbuf[n * 4 + 2] = (am == 2) ? TAU : lo;
        if (mv - sec < GAPT) {
            int s = atomicAdd(&scnt, 1);
            snode[s] = n;
        }
    }
    __syncthreads();
    int cnt = scnt;
    int w = t >> 6, l = t & 63;
    for (int it = 0; it < cnt; it++) {
        int n = snode[it];
        for (int k = t; k < 768; k += 256) xs[k] = x1[(size_t)n * 768 + k];
        __syncthreads();
        {
            float acc[8] = {0.f, 0.f, 0.f, 0.f, 0.f, 0.f, 0.f, 0.f};
            for (int k = w * 192; k < (w + 1) * 192; k++) {
                float xv = xs[k];
                const float* wr = W1 + (size_t)k * 512 + l;
#pragma unroll
                for (int c = 0; c < 8; c++) acc[c] += xv * wr[64 * c];
            }
#pragma unroll
            for (int c = 0; c < 8; c++) part[w][l + 64 * c] = acc[c];
        }
        __syncthreads();
        for (int d = t; d < 512; d += 256)
            h1[d] = fmaxf(part[0][d] + part[1][d] + part[2][d] + part[3][d] + b1[d], 0.f);
        __syncthreads();
        {
            float acc[8] = {0.f, 0.f, 0.f, 0.f, 0.f, 0.f, 0.f, 0.f};
            for (int k = w * 128; k < (w + 1) * 128; k++) {
                float xv = h1[k];
                const float* wr = W2 + (size_t)k * 512 + l;
#pragma unroll
                for (int c = 0; c < 8; c++) acc[c] += xv * wr[64 * c];
            }
#pragma unroll
            for (int c = 0; c < 8; c++) part[w][l + 64 * c] = acc[c];
        }
        __syncthreads();
        for (int d = t; d < 512; d += 256)
            h2[d] = fmaxf(part[0][d] + part[1][d] + part[2][d] + part[3][d] + b2[d], 0.f);
        __syncthreads();
        if (t < 64) {
            float p0 = 0.f, p1 = 0.f, p2 = 0.f;
            for (int k = t; k < 512; k += 64) {
                float hv = h2[k];
                p0 += hv * W3[k * 3 + 0];
                p1 += hv * W3[k * 3 + 1];
                p2 += hv * W3[k * 3 + 2];
            }
            for (int off = 32; off; off >>= 1) {
                p0 += __shfl_down(p0, off);
                p1 += __shfl_down(p1, off);
                p2 += __shfl_down(p2, off);
            }
            if (t == 0) {
                float l0 = p0 + b3[0], l1 = p1 + b3[1], l2 = p2 + b3[2];
                int am = 0;
                float mv = l0;
                if (l1 > mv) { mv = l1; am = 1; }
                if (l2 > mv) { mv = l2; am = 2; }
                float lo = (1.f - TAU) * 0.5f;
                rbuf[n * 4 + 0] = (am == 0) ? TAU : lo;
                rbuf[n * 4 + 1] = (am == 1) ? TAU : lo;
                rbuf[n * 4 + 2] = (am == 2) ? TAU : lo;
            }
        }
        __syncthreads();
    }
}

// =============== res1 -> bf16 hi/lo (R7 verbatim) ===============
__global__ __launch_bounds__(256) void res1_kernel(
    const float* __restrict__ x2, const float* __restrict__ G, const float* __restrict__ m1b3,
    const float* __restrict__ rbuf, const float* __restrict__ C2s, const float* __restrict__ bp1,
    const float* __restrict__ Wm1s, const float* __restrict__ bp2,
    ushort* __restrict__ r1h, ushort* __restrict__ r1l) {
    int idx = blockIdx.x * 256 + threadIdx.x;
    int n = idx / 192;
    int kq = (idx % 192) * 4;
    float g0 = G[n * 2 + 0] + m1b3[0], g1 = G[n * 2 + 1] + m1b3[1];
    float r0 = rbuf[n * 4 + 0], r1 = rbuf[n * 4 + 1], r2 = rbuf[n * 4 + 2];
    float4 xv = *(const float4*)(x2 + (size_t)n * 768 + kq);
    float4 c0 = *(const float4*)(C2s + kq);
    float4 c1 = *(const float4*)(C2s + 768 + kq);
    float4 p0 = *(const float4*)(bp1 + kq);
    float4 p1 = *(const float4*)(bp1 + 768 + kq);
    float4 w0 = *(const float4*)(Wm1s + kq);
    float4 w1 = *(const float4*)(Wm1s + 768 + kq);
    float4 w2 = *(const float4*)(Wm1s + 1536 + kq);
    float4 q0 = *(const float4*)(bp2 + kq);
    float4 q1 = *(const float4*)(bp2 + 768 + kq);
    float4 q2 = *(const float4*)(bp2 + 1536 + kq);
    float o[4];
    o[0] = (xv.x * (g0 * c0.x + g1 * c1.x) + g0 * p0.x + g1 * p1.x) * (r0 * w0.x + r1 * w1.x + r2 * w2.x) + r0 * q0.x + r1 * q1.x + r2 * q2.x;
    o[1] = (xv.y * (g0 * c0.y + g1 * c1.y) + g0 * p0.y + g1 * p1.y) * (r0 * w0.y + r1 * w1.y + r2 * w2.y) + r0 * q0.y + r1 * q1.y + r2 * q2.y;
    o[2] = (xv.z * (g0 * c0.z + g1 * c1.z) + g0 * p0.z + g1 * p1.z) * (r0 * w0.z + r1 * w1.z + r2 * w2.z) + r0 * q0.z + r1 * q1.z + r2 * q2.z;
    o[3] = (xv.w * (g0 * c0.w + g1 * c1.w) + g0 * p0.w + g1 * p1.w) * (r0 * w0.w + r1 * w1.w + r2 * w2.w) + r0 * q0.w + r1 * q1.w + r2 * q2.w;
    ushort h[4], l[4];
#pragma unroll
    for (int i = 0; i < 4; i++) bf16split(o[i], h[i], l[i]);
    size_t off = ((size_t)n * 768 + kq) / 4;
    ((ushort4*)r1h)[off] = make_ushort4(h[0], h[1], h[2], h[3]);
    ((ushort4*)r1l)[off] = make_ushort4(l[0], l[1], l[2], l[3]);
}

// =============== gather1 + combine -> res2 (f32) ===============
__global__ __launch_bounds__(256) void gather1_combine(
    const float* __restrict__ gcw, const int* __restrict__ rowst, const int* __restrict__ adj,
    const float* __restrict__ dinv, const float* __restrict__ gcn1_b,
    const float* __restrict__ rbuf, const float* __restrict__ wm12,
    const float* __restrict__ Wm2s, float* __restrict__ res2f) {
    int n = blockIdx.x;
    int k = threadIdx.x;
    int lane = threadIdx.x & 63;
    int e0 = rowst[n], e1 = rowst[n + 1];
    float acc = 0.f;
    for (int base = e0; base < e1; base += 64) {
        int idx = base + lane;
        int s_i = 0;
        float w_i = 0.f;
        if (idx < e1) { s_i = adj[idx]; w_i = dinv[s_i]; }
        int mm = min(64, e1 - base);
        for (int j = 0; j < mm; j++) {
            int s = __shfl(s_i, j);
            float w = __shfl(w_i, j);
            acc += gcw[(size_t)s * 512 + k] * w;
        }
    }
    float h1 = dinv[n] * acc + gcn1_b[k];
    float mv = gcw[(size_t)n * 512 + 256 + k];
    float r0 = rbuf[n * 4 + 0], r1 = rbuf[n * 4 + 1], r2 = rbuf[n * 4 + 2];
    float a = r0 * wm12[k] + r1 * wm12[256 + k] + r2 * wm12[512 + k];
    float w = r0 * Wm2s[k] + r1 * Wm2s[256 + k] + r2 * Wm2s[512 + k];
    res2f[(size_t)n * 256 + k] = w * (a * fmaxf(h1, 0.f) + 2e-4f * mv);
}

// =============== gather(res2) -> @gcn2_W + b -> relu -> fc -> log_softmax ===============
__global__ __launch_bounds__(256) void gather2_full(
    const float* __restrict__ res2f, const int* __restrict__ rowst,
    const int* __restrict__ adj, const float* __restrict__ dinv,
    const float* __restrict__ G2W, const float* __restrict__ gcn2_b,
    const float* __restrict__ fcW, const float* __restrict__ fcb,
    float* __restrict__ out) {
    __shared__ float gres[256];
    __shared__ float part[8][32];
    int t = threadIdx.x;
    int lane = t & 63;
    int n = blockIdx.x;
    int e0 = rowst[n], e1 = rowst[n + 1];
    float acc = 0.f;
    for (int base = e0; base < e1; base += 64) {
        int idx = base + lane;
        int s_i = 0;
        float w_i = 0.f;
        if (idx < e1) { s_i = adj[idx]; w_i = dinv[s_i]; }
        int mm = min(64, e1 - base);
        for (int j = 0; j < mm; j++) {
            int s = __shfl(s_i, j);
            float w = __shfl(w_i, j);
            acc += res2f[(size_t)s * 256 + t] * w;
        }
    }
    gres[t] = acc * dinv[n];
    __syncthreads();
    int j = t & 31, seg = t >> 5;
    float p = 0.f;
#pragma unroll
    for (int kk = 0; kk < 32; kk++) {
        int k = seg * 32 + kk;
        p += gres[k] * G2W[k * 32 + j];
    }
    part[seg][j] = p;
    __syncthreads();
    if (t < 32) {
        float h2 = part[0][t] + part[1][t] + part[2][t] + part[3][t] +
                   part[4][t] + part[5][t] + part[6][t] + part[7][t] + gcn2_b[t];
        gres[t] = fmaxf(h2, 0.f);
    }
    __syncthreads();
    if (t < 8) {
        float logit = fcb[t];
#pragma unroll
        for (int i = 0; i < 32; i++) logit += gres[i] * fcW[i * 8 + t];
        float m = logit;
        for (int off = 4; off; off >>= 1) m = fmaxf(m, __shfl_xor(m, off, 8));
        float e = expf(logit - m), s = e;
        for (int off = 4; off; off >>= 1) s += __shfl_xor(s, off, 8);
        out[(size_t)n * 8 + t] = logit - m - logf(s);
    }
}

extern "C" void kernel_launch(void* const* d_in, const int* in_sizes, int n_in,
                              void* d_out, int out_size, void* d_ws, size_t ws_size,
                              hipStream_t stream) {
    const float* x1     = (const float*)d_in[0];
    const float* x11    = (const float*)d_in[1];
    const float* x2     = (const float*)d_in[2];
    const float* mlp_W1 = (const float*)d_in[3];
    const float* mlp_b1 = (const float*)d_in[4];
    const float* mlp_W2 = (const float*)d_in[5];
    const float* mlp_b2 = (const float*)d_in[6];
    const float* mlp_W3 = (const float*)d_in[7];
    const float* mlp_b3 = (const float*)d_in[8];
    const float* m1_W1  = (const float*)d_in[9];
    const float* m1_b1  = (const float*)d_in[10];
    const float* m1_W2  = (const float*)d_in[11];
    const float* m1_b2  = (const float*)d_in[12];
    const float* m1_W3  = (const float*)d_in[13];
    const float* m1_b3  = (const float*)d_in[14];
    const float* wm1    = (const float*)d_in[15];
    const float* bp1    = (const float*)d_in[16];
    const float* bp2    = (const float*)d_in[17];
    const float* wm12   = (const float*)d_in[18];
    const float* wm13   = (const float*)d_in[19];
    const float* class2 = (const float*)d_in[20];
    const float* gcn1_W = (const float*)d_in[21];
    const float* gcn1_b = (const float*)d_in[22];
    const float* wm2    = (const float*)d_in[23];
    const float* gcn2_W = (const float*)d_in[24];
    const float* gcn2_b = (const float*)d_in[25];
    const float* fc_W   = (const float*)d_in[26];
    const float* fc_b   = (const float*)d_in[27];
    const int* eidx     = (const int*)d_in[28];
    const int* esrc = eidx;
    const int* edst = eidx + NE;

    char* ws = (char*)d_ws;
    ushort* XH1   = (ushort*)(ws + 0x0000000);
    ushort* XL1   = (ushort*)(ws + 0x0180000);
    ushort* XH2   = (ushort*)(ws + 0x0300000);
    ushort* XL2   = (ushort*)(ws + 0x0480000);
    ushort* W1AH  = (ushort*)(ws + 0x0600000);
    ushort* W1AL  = (ushort*)(ws + 0x06C0000);
    ushort* W1BH  = (ushort*)(ws + 0x0780000);
    ushort* W1BL  = (ushort*)(ws + 0x0840000);
    ushort* W2AH  = (ushort*)(ws + 0x0900000);
    ushort* W2AL  = (ushort*)(ws + 0x0980000);
    ushort* W2BH  = (ushort*)(ws + 0x0A00000);
    ushort* W2BL  = (ushort*)(ws + 0x0A80000);
    ushort* GWH   = (ushort*)(ws + 0x0B00000);
    ushort* GWL   = (ushort*)(ws + 0x0BC0000);
    ushort* HS1AH = (ushort*)(ws + 0x0D00000);
    ushort* HS1AL = (ushort*)(ws + 0x0E00000);
    ushort* HS1BH = (ushort*)(ws + 0x0F00000);
    ushort* HS1BL = (ushort*)(ws + 0x1000000);
    ushort* RES1H = (ushort*)(ws + 0x1100000);
    ushort* RES1L = (ushort*)(ws + 0x1280000);
    float*  GCW   = (float*)(ws + 0x1400000);
    float*  RES2F = (float*)(ws + 0x1600000);
    float* LOGITS = (float*)(ws + 0x1740000);
    float* GBUF   = (float*)(ws + 0x1744000);
    float* RBUF   = (float*)(ws + 0x1746000);
    float* DINV   = (float*)(ws + 0x174A000);
    int*   ROWST  = (int*)(ws + 0x174B000);
    int*   CURS   = (int*)(ws + 0x174D000);
    int*   ADJ    = (int*)(ws + 0x174E000);
    int*   PART   = (int*)(ws + 0x1780000);   // [8][1024]
    float* C2S    = (float*)(ws + 0x1770000);
    float* WM1S   = (float*)(ws + 0x1772000);
    float* WM2S   = (float*)(ws + 0x1775000);

    // D0: prep (splits/transposes/tables/zero) + LDS-hist degree count (no memset needed)
    aux0<<<1025, 1024, 0, stream>>>(class2, wm1, wm2, C2S, WM1S, WM2S, LOGITS,
                                    x1, XH1, XL1, x11, XH2, XL2,
                                    mlp_W1, W1AH, W1AL, m1_W1, W1BH, W1BL,
                                    mlp_W2, W2AH, W2AL, m1_W2, W2BH, W2BL,
                                    gcn1_W, GWH, GWL, wm13, edst, PART);
    // D1: L1 pair + CSR scan rider (sums partials)
    gemm_pair<768, 1, 1, 1><<<513, 256, 0, stream>>>(
        XH1, XL1, W1AH, W1AL, mlp_b1, nullptr, nullptr, HS1AH, HS1AL,
        XH2, XL2, W1BH, W1BL, m1_b1, nullptr, nullptr, HS1BH, HS1BL,
        esrc, edst, PART, ROWST, CURS, DINV, ADJ);
    // D2: L2 pair (logits + g accum) + adj-fill riders
    gemm_pair<512, 2, 3, 2><<<640, 256, 0, stream>>>(
        HS1AH, HS1AL, W2AH, W2AL, mlp_b2, mlp_W3, LOGITS, nullptr, nullptr,
        HS1BH, HS1BL, W2BH, W2BL, m1_b2, m1_W3, GBUF, nullptr, nullptr,
        esrc, edst, PART, ROWST, CURS, DINV, ADJ);
    // D3: finalize routing + block-local exact repair
    finrep<<<256, 256, 0, stream>>>(LOGITS, mlp_b3, RBUF, x1, mlp_W1, mlp_b1,
                                    mlp_W2, mlp_b2, mlp_W3);
    // D4: res1
    res1_kernel<<<768, 256, 0, stream>>>(x2, GBUF, m1_b3, RBUF, C2S, bp1, WM1S, bp2,
                                         RES1H, RES1L);
    // D5: gcw = res1 @ [gcn1_W | wm13]  (16-col jobs: 2048 waves for latency hiding)
    gemm3_n16<1024, 512, 768><<<512, 256, 0, stream>>>(RES1H, RES1L, GWH, GWL, GCW);
    // D6: gather1 + combine -> res2 (f32)
    gather1_combine<<<NN, 256, 0, stream>>>(GCW, ROWST, ADJ, DINV, gcn1_b, RBUF,
                                            wm12, WM2S, RES2F);
    // D7: gather(res2) @ gcn2_W + relu + fc + log_softmax
    gather2_full<<<NN, 256, 0, stream>>>(RES2F, ROWST, ADJ, DINV, gcn2_b ? gcn2_W : gcn2_W,
                                         gcn2_b, fc_W, fc_b, (float*)d_out);
}